// Round 14
// baseline (1327.941 us; speedup 1.0000x reference)
//
#include <hip/hip_runtime.h>

// Bidirectional masked LSTM, only last timestep consumed.
//   B=256, T=2048, VOCAB=6, EMB=64, HID=64.
// Algebraic reductions (validated rounds 0-13, absmax 0.0):
//   - bwd direction at t=T-1 == ONE lstm step from zero state (U_b unused).
//   - x@W+b has only 6 values per direction -> zx tables.
//   - tok==0 steps are no-ops -> token stream compacted once.
// Ledger: R6/R12 703us (4-wave, U spilled, VGPR 52); R13 731us (4-wave,
//   waves_per_eu(1,1), U RESIDENT, VGPR 132) -> U storage was NEVER the
//   bottleneck. Per-step 1030cyc = ~500 VALU issue + ~530 stall, and the
//   stall is the cross-wave act exchange (ds_write+barrier+4x ds_read+
//   replicated update) that exists only because gates live in 4 waves.
// Round-14: SINGLE-WAVE kernel. 1 wave/sequence, lane u owns unit u and all
//   4 gates -> c/h update lane-local, ZERO LDS/barrier in the loop except a
//   single float4 zx read + token prefetch. U as 128 float2 (ext_vector) ->
//   v_pk_fma_f32 candidates; 256 VGPRs under the waves_per_eu(1,1) budget.
// Predicted: dur 731 -> 380-540us; VGPR -> ~280-330 (KEY readout);
//   VALUBusy -> 80-95%; bank conflicts ~0.

#define TT 2048
#define L2E 1.4426950408889634f

typedef float v2f __attribute__((ext_vector_type(2)));

__device__ __forceinline__ float fexp2(float x) { return __builtin_amdgcn_exp2f(x); }
__device__ __forceinline__ float frcp(float x)  { return __builtin_amdgcn_rcpf(x); }
__device__ __forceinline__ float fsigm(float x) { return frcp(1.f + fexp2(-L2E * x)); }
__device__ __forceinline__ float ftanh(float x) { return fmaf(2.f, frcp(1.f + fexp2(-2.f * L2E * x)), -1.f); }
__device__ __forceinline__ float readlane_f(float v, int l) {
  return __builtin_bit_cast(float, __builtin_amdgcn_readlane(__builtin_bit_cast(int, v), l));
}

__global__ void
__attribute__((amdgpu_flat_work_group_size(64, 64)))
__attribute__((amdgpu_waves_per_eu(1, 1)))
lstm_fused(
    const int* __restrict__ tokens,
    const float* __restrict__ emb,
    const float* __restrict__ W_f, const float* __restrict__ U_f, const float* __restrict__ b_f,
    const float* __restrict__ W_b, const float* __restrict__ b_b,
    const float* __restrict__ W_d, const float* __restrict__ b_d,
    float* __restrict__ out)
{
  const int b = blockIdx.x;
  const int u = threadIdx.x;            // 0..63: hidden unit AND lane

  __shared__ int   tok_s [TT];
  __shared__ int   ctok_s[TT + 8];      // compacted active tokens
  __shared__ float emb_s[6 * 64];
  __shared__ float zx_s [6 * 256] __attribute__((aligned(16)));  // [v][u][gate]
  __shared__ float zxb_s[6 * 256] __attribute__((aligned(16)));  // bwd, same layout

  // ---- stage tokens (int4, coalesced) + emb ----
  {
    const int4* tsrc = (const int4*)(tokens + b * TT);
    int4* tdst = (int4*)tok_s;
    for (int i = u; i < TT / 4; i += 64) tdst[i] = tsrc[i];
    for (int i = u; i < 384; i += 64) emb_s[i] = emb[i];
  }
  __syncthreads();

  // ---- compact active tokens: 32 tokens/lane, wave scan (stable) ----
  int cnt = 0;
  for (int j = 0; j < 32; ++j) cnt += (tok_s[u * 32 + j] != 0);
  int inc = cnt;
#pragma unroll
  for (int off = 1; off < 64; off <<= 1) {
    int v = __shfl_up(inc, off, 64);
    if (u >= off) inc += v;
  }
  int pos = inc - cnt;                  // exclusive offset
  for (int j = 0; j < 32; ++j) {
    const int t = tok_s[u * 32 + j];
    if (t != 0) ctok_s[pos++] = t;
  }
  const int nact = __builtin_amdgcn_readfirstlane(__shfl(inc, 63, 64));
  if (u < 8) ctok_s[nact + u] = 0;      // prefetch pad
  __syncthreads();

  // ---- zx tables, packed [v][u][gate] (fwd and bwd) ----
#pragma unroll
  for (int g4 = 0; g4 < 4; ++g4) {
    const int col = g4 * 64 + u;
    float af[6], ab[6];
#pragma unroll
    for (int v = 0; v < 6; ++v) { af[v] = b_f[col]; ab[v] = b_b[col]; }
    for (int e = 0; e < 64; ++e) {
      const float wf = W_f[e * 256 + col];
      const float wb = W_b[e * 256 + col];
#pragma unroll
      for (int v = 0; v < 6; ++v) {
        af[v] = fmaf(emb_s[v * 64 + e], wf, af[v]);
        ab[v] = fmaf(emb_s[v * 64 + e], wb, ab[v]);
      }
    }
#pragma unroll
    for (int v = 0; v < 6; ++v) {
      zx_s [v * 256 + u * 4 + g4] = af[v];
      zxb_s[v * 256 + u * 4 + g4] = ab[v];
    }
  }

  // ---- U fragments: lane u holds all 4 gate columns of unit u, packed
  //      (i,f) and (g,o) pairs -> v_pk_fma_f32 candidates. 256 VGPRs;
  //      resident under the waves_per_eu(1,1) 512-reg budget (R13 readout).
  v2f U01[64], U23[64];
#pragma unroll
  for (int k = 0; k < 64; ++k) {
    U01[k] = v2f{U_f[k * 256 + u],       U_f[k * 256 + 64 + u]};
    U23[k] = v2f{U_f[k * 256 + 128 + u], U_f[k * 256 + 192 + u]};
  }

  __syncthreads();

  // ---- recurrence: no barriers, no cross-wave traffic ----
  float h_reg = 0.f, c_reg = 0.f;
  int tokc = ctok_s[0];

  for (int s = 0; s < nact; ++s) {
    const int tokn = ctok_s[s + 1];     // prefetch (pad-safe)
    const float4 zx4 = *(const float4*)&zx_s[tokc * 256 + u * 4];
    v2f a01 = v2f{zx4.x, zx4.y}, a23 = v2f{zx4.z, zx4.w};
    v2f b01 = v2f{0.f, 0.f},     b23 = v2f{0.f, 0.f};
#pragma unroll
    for (int k = 0; k < 64; k += 2) {
      const float h0 = readlane_f(h_reg, k);
      const float h1 = readlane_f(h_reg, k + 1);
      a01 += U01[k] * h0;       a23 += U23[k] * h0;
      b01 += U01[k + 1] * h1;   b23 += U23[k + 1] * h1;
    }
    const v2f z01 = a01 + b01;          // (z_i, z_f)
    const v2f z23 = a23 + b23;          // (z_g, z_o)
    const float yi = fsigm(z01.x);
    const float yf = fsigm(z01.y);
    const float yg = ftanh(z23.x);
    const float yo = fsigm(z23.y);
    c_reg = fmaf(yf, c_reg, yi * yg);
    h_reg = yo * ftanh(c_reg);
    tokc = tokn;
  }

  // ---- epilogue: bwd single step from zero state + dense + reduce ----
  const int tokL = tok_s[TT - 1];
  float hbv = 0.f;
  if (tokL != 0) {                      // uniform branch
    const float4 zb = *(const float4*)&zxb_s[tokL * 256 + u * 4];
    const float cn = fsigm(zb.x) * ftanh(zb.z);   // c0=0 -> forget term vanishes
    hbv = fsigm(zb.w) * ftanh(cn);
  }
  float pr = fmaf(h_reg, W_d[u], hbv * W_d[64 + u]);
#pragma unroll
  for (int off = 32; off > 0; off >>= 1) pr += __shfl_xor(pr, off, 64);
  if (u == 0) out[b] = pr + b_d[0];
}

extern "C" void kernel_launch(void* const* d_in, const int* in_sizes, int n_in,
                              void* d_out, int out_size, void* d_ws, size_t ws_size,
                              hipStream_t stream) {
  const int*   tokens = (const int*)d_in[0];
  const float* emb    = (const float*)d_in[1];
  const float* W_f    = (const float*)d_in[2];
  const float* U_f    = (const float*)d_in[3];
  const float* b_f    = (const float*)d_in[4];
  const float* W_b    = (const float*)d_in[5];
  const float* U_b    = (const float*)d_in[6];
  (void)U_b;  // bwd is a single step from zero state: h@U_b == 0
  const float* b_b    = (const float*)d_in[7];
  const float* W_d    = (const float*)d_in[8];
  const float* b_d    = (const float*)d_in[9];
  float* out = (float*)d_out;
  (void)d_ws; (void)ws_size;

  lstm_fused<<<256, 64, 0, stream>>>(tokens, emb, W_f, U_f, b_f, W_b, b_b,
                                     W_d, b_d, out);
}

// Round 15
// 861.779 us; speedup vs baseline: 1.5409x; 1.5409x over previous
//
#include <hip/hip_runtime.h>

// Bidirectional masked LSTM, only last timestep consumed.
//   B=256, T=2048, VOCAB=6, EMB=64, HID=64.  One 4-wave block per sequence/CU.
// Algebraic reductions (validated rounds 0-14, absmax 0.0):
//   - bwd direction at t=T-1 == ONE lstm step from zero state (U_b unused).
//   - x@W+b has only 6 values per direction -> zx tables.
//   - tok==0 steps are no-ops -> token stream compacted once.
// Ledger: R6/R12 703us (gate-split waves, U spilled); R13 731us (U resident;
//   proves U storage not the limiter); R14 single-wave 1307us (256 U floats
//   unreachable, 1 SIMD). R13 breakdown: ~500 VALU (incl ~200 readlane->fma
//   SGPR-hazard waits) + ~530 tail (act exchange + replicated update).
// Round-15: UNIT-SPLIT waves. Wave w owns units [16w,16w+16); lane=(gate,ul).
//   All 4 gates of a unit in ONE wave -> gather via 3 shuffles, update once
//   (lanes 0-15), only h crosses waves: 16 ds_write + barrier + 1 ds_read
//   (double-buffered). Plus R11's pipelined readlane groups (now honorable
//   under the waves_per_eu(1,1) register budget).
// Predicted: dur 731 -> 450-550us; VGPR 140-190; VALUBusy 55-70%; absmax 0.

#define TT 2048
#define L2E 1.4426950408889634f

__device__ __forceinline__ float fexp2(float x) { return __builtin_amdgcn_exp2f(x); }
__device__ __forceinline__ float frcp(float x)  { return __builtin_amdgcn_rcpf(x); }
__device__ __forceinline__ float fsigm(float x) { return frcp(1.f + fexp2(-L2E * x)); }
__device__ __forceinline__ float ftanh(float x) { return fmaf(2.f, frcp(1.f + fexp2(-2.f * L2E * x)), -1.f); }
__device__ __forceinline__ float readlane_f(float v, int l) {
  return __builtin_bit_cast(float, __builtin_amdgcn_readlane(__builtin_bit_cast(int, v), l));
}

// broadcast group of 16: h[base..base+16) -> SGPR uniforms
#define RL16(B, base)                                                             \
  B[0]  = readlane_f(h_reg, (base) + 0);  B[1]  = readlane_f(h_reg, (base) + 1);  \
  B[2]  = readlane_f(h_reg, (base) + 2);  B[3]  = readlane_f(h_reg, (base) + 3);  \
  B[4]  = readlane_f(h_reg, (base) + 4);  B[5]  = readlane_f(h_reg, (base) + 5);  \
  B[6]  = readlane_f(h_reg, (base) + 6);  B[7]  = readlane_f(h_reg, (base) + 7);  \
  B[8]  = readlane_f(h_reg, (base) + 8);  B[9]  = readlane_f(h_reg, (base) + 9);  \
  B[10] = readlane_f(h_reg, (base) + 10); B[11] = readlane_f(h_reg, (base) + 11); \
  B[12] = readlane_f(h_reg, (base) + 12); B[13] = readlane_f(h_reg, (base) + 13); \
  B[14] = readlane_f(h_reg, (base) + 14); B[15] = readlane_f(h_reg, (base) + 15);

// FMA group of 16 consuming broadcast buffer B against Ucol[base..base+16)
#define FMA16(B, base)                                                       \
  a0 = fmaf(B[0],  Ucol[(base) + 0],  a0); a1 = fmaf(B[1],  Ucol[(base) + 1],  a1); \
  a2 = fmaf(B[2],  Ucol[(base) + 2],  a2); a3 = fmaf(B[3],  Ucol[(base) + 3],  a3); \
  a0 = fmaf(B[4],  Ucol[(base) + 4],  a0); a1 = fmaf(B[5],  Ucol[(base) + 5],  a1); \
  a2 = fmaf(B[6],  Ucol[(base) + 6],  a2); a3 = fmaf(B[7],  Ucol[(base) + 7],  a3); \
  a0 = fmaf(B[8],  Ucol[(base) + 8],  a0); a1 = fmaf(B[9],  Ucol[(base) + 9],  a1); \
  a2 = fmaf(B[10], Ucol[(base) + 10], a2); a3 = fmaf(B[11], Ucol[(base) + 11], a3); \
  a0 = fmaf(B[12], Ucol[(base) + 12], a0); a1 = fmaf(B[13], Ucol[(base) + 13], a1); \
  a2 = fmaf(B[14], Ucol[(base) + 14], a2); a3 = fmaf(B[15], Ucol[(base) + 15], a3);

__global__ void
__attribute__((amdgpu_flat_work_group_size(256, 256)))
__attribute__((amdgpu_waves_per_eu(1, 1)))
lstm_fused(
    const int* __restrict__ tokens,
    const float* __restrict__ emb,
    const float* __restrict__ W_f, const float* __restrict__ U_f, const float* __restrict__ b_f,
    const float* __restrict__ W_b, const float* __restrict__ b_b,
    const float* __restrict__ W_d, const float* __restrict__ b_d,
    float* __restrict__ out)
{
  const int b    = blockIdx.x;
  const int tid  = threadIdx.x;
  const int lane = tid & 63;
  const int w    = tid >> 6;      // wave: owns units [16w, 16w+16)
  const int g    = lane >> 4;     // gate 0:i 1:f 2:g(tanh) 3:o
  const int ul   = lane & 15;     // unit within wave's group
  const int u    = 16 * w + ul;   // hidden unit this lane's column belongs to
  const int col  = (g << 6) + u;  // column in z / U

  __shared__ int   tok_s [TT + 8];
  __shared__ int   ctok_s[TT + 8];      // compacted active tokens
  __shared__ float emb_s[6 * 64];
  __shared__ float zx_s [6 * 272];      // fwd table, [v][g*68 + u] (padded)
  __shared__ float zxb_s[6 * 256];      // bwd table (epilogue only)
  __shared__ float h_s[2][64];          // double-buffered h exchange
  __shared__ int   wsum[4];

  // ---- stage tokens (int4) + emb; zero h buffers ----
  {
    const int4* tsrc = (const int4*)(tokens + b * TT);
    int4* tdst = (int4*)tok_s;
    for (int i = tid; i < TT / 4; i += 256) tdst[i] = tsrc[i];
    if (tid < 8) { tok_s[TT + tid] = 0; ctok_s[TT + tid] = 0; }
    for (int i = tid; i < 384; i += 256) emb_s[i] = emb[i];
    if (tid < 64) { h_s[0][tid] = 0.f; h_s[1][tid] = 0.f; }
  }
  __syncthreads();

  // ---- compact active tokens: stable parallel scan (8 tokens/thread) ----
  int mytok[8];
  int cnt = 0;
#pragma unroll
  for (int j = 0; j < 8; ++j) {
    mytok[j] = tok_s[tid * 8 + j];
    cnt += (mytok[j] != 0);
  }
  int inc = cnt;                        // wave-inclusive scan
#pragma unroll
  for (int off = 1; off < 64; off <<= 1) {
    int v = __shfl_up(inc, off, 64);
    if (lane >= off) inc += v;
  }
  if (lane == 63) wsum[w] = inc;
  __syncthreads();
  int base = 0;
#pragma unroll
  for (int ww = 0; ww < 4; ++ww) base += (ww < w) ? wsum[ww] : 0;
  int pos = base + inc - cnt;           // exclusive global offset
#pragma unroll
  for (int j = 0; j < 8; ++j)
    if (mytok[j] != 0) ctok_s[pos++] = mytok[j];
  const int nact = __builtin_amdgcn_readfirstlane(wsum[0] + wsum[1] + wsum[2] + wsum[3]);

  // ---- zx tables (thread builds column tid, both dirs) ----
  {
    float af[6], ab[6];
#pragma unroll
    for (int v = 0; v < 6; ++v) { af[v] = b_f[tid]; ab[v] = b_b[tid]; }
    for (int e = 0; e < 64; ++e) {
      const float wf = W_f[e * 256 + tid];
      const float wb = W_b[e * 256 + tid];
#pragma unroll
      for (int v = 0; v < 6; ++v) {
        af[v] = fmaf(emb_s[v * 64 + e], wf, af[v]);
        ab[v] = fmaf(emb_s[v * 64 + e], wb, ab[v]);
      }
    }
#pragma unroll
    for (int v = 0; v < 6; ++v) {
      zx_s [v * 272 + (tid >> 6) * 68 + (tid & 63)] = af[v];
      zxb_s[v * 256 + tid] = ab[v];
    }
  }

  // ---- U column for this lane's (gate g, unit u): plain register array,
  //      resident under the waves_per_eu(1,1) budget (R13 readout) ----
  float Ucol[64];
#pragma unroll
  for (int k = 0; k < 64; ++k) Ucol[k] = U_f[k * 256 + col];

  __syncthreads();

  // per-lane activation constants: y = ya*rcp(1+exp2(z*m1)) + yb
  const float m1 = (g == 2) ? (-2.f * L2E) : (-L2E);
  const float ya = (g == 2) ? 2.f : 1.f;
  const float yb = (g == 2) ? -1.f : 0.f;
  const int   goff = g * 68 + u;        // zx index

  float h_reg = 0.f;                    // every lane: h[unit = lane]
  float c_reg = 0.f;                    // valid on lanes 0-15 (g==0): c[u]
  int   buf = 0;
  int   tokc = ctok_s[0];

  for (int s = 0; s < nact; ++s) {
    const int tokn = ctok_s[s + 1];              // prefetch (pad-safe)
    const float zxv = zx_s[tokc * 272 + goff];   // hides under FMA block
    float a0 = 0.f, a1 = 0.f, a2 = 0.f, a3 = 0.f;
    float hsA[16], hsB[16];
    // pipelined broadcast: every SGPR written >=16 instrs before first read
    RL16(hsA, 0)
    RL16(hsB, 16)
    FMA16(hsA, 0)
    RL16(hsA, 32)
    FMA16(hsB, 16)
    RL16(hsB, 48)
    FMA16(hsA, 32)
    FMA16(hsB, 48)
    const float z = zxv + ((a0 + a1) + (a2 + a3));
    const float y = fmaf(ya, frcp(1.f + fexp2(z * m1)), yb);
    // gather f,g,o for unit u onto the g==0 lanes (intra-wave, no barrier)
    const float vf = __shfl(y, ul + 16, 64);
    const float vg = __shfl(y, ul + 32, 64);
    const float vo = __shfl(y, ul + 48, 64);
    c_reg = fmaf(vf, c_reg, y * vg);             // y == i-act on g==0 lanes
    const float hn = vo * ftanh(c_reg);
    if (lane < 16) h_s[buf ^ 1][u] = hn;         // 16 writes per wave
    __syncthreads();
    buf ^= 1;
    h_reg = h_s[buf][lane];                      // 1 read per lane
    tokc = tokn;
  }

  // ---- epilogue: bwd single step from zero state + dense + reduce ----
  if (tid < 64) {                                // wave 0: h_reg == h[tid]
    const float hf   = h_reg;
    const int   tokL = tok_s[TT - 1];
    float hbv = 0.f;
    if (tokL != 0) {
      const float zi = zxb_s[tokL * 256 + tid];
      const float zg = zxb_s[tokL * 256 + 128 + tid];
      const float zo = zxb_s[tokL * 256 + 192 + tid];
      const float cn = fsigm(zi) * ftanh(zg);    // c0=0 -> forget term vanishes
      hbv = fsigm(zo) * ftanh(cn);
    }
    float pr = fmaf(hf, W_d[tid], hbv * W_d[64 + tid]);
#pragma unroll
    for (int off = 32; off > 0; off >>= 1) pr += __shfl_xor(pr, off, 64);
    if (tid == 0) out[b] = pr + b_d[0];
  }
}

extern "C" void kernel_launch(void* const* d_in, const int* in_sizes, int n_in,
                              void* d_out, int out_size, void* d_ws, size_t ws_size,
                              hipStream_t stream) {
  const int*   tokens = (const int*)d_in[0];
  const float* emb    = (const float*)d_in[1];
  const float* W_f    = (const float*)d_in[2];
  const float* U_f    = (const float*)d_in[3];
  const float* b_f    = (const float*)d_in[4];
  const float* W_b    = (const float*)d_in[5];
  const float* U_b    = (const float*)d_in[6];
  (void)U_b;  // bwd is a single step from zero state: h@U_b == 0
  const float* b_b    = (const float*)d_in[7];
  const float* W_d    = (const float*)d_in[8];
  const float* b_d    = (const float*)d_in[9];
  float* out = (float*)d_out;
  (void)d_ws; (void)ws_size;

  lstm_fused<<<256, 256, 0, stream>>>(tokens, emb, W_f, U_f, b_f, W_b, b_b,
                                      W_d, b_d, out);
}